// Round 6
// baseline (8954.310 us; speedup 1.0000x reference)
//
#include <hip/hip_runtime.h>
#include <hip/hip_fp16.h>
#include <cstdint>
#include <cstddef>

// ---------------------------------------------------------------------------
// EnDeModel: GRU encoder (365) -> GRU decoder (90) -> SIRD rollout
// R6: 128 WGs x 512 threads; each wave owns an ADJACENT UNIT PAIR
// (ja=wg*16+2*wave, jb=ja+1). All weights fp16 in registers:
//   enc Whh: 6 rows/wave (96 VGPR), dec Wih+Whh: 12 rows/wave (192 VGPR).
// After the interleaved butterfly reduce EVERY lane holds all row sums, so
// lanes 0-7 redundantly compute the gates and store the packed fp16-pair u64
// {tag | fp16 hb | fp16 ha} straight to replica `lane` -- no LDS pack, no
// producer-side __syncthreads. The trailing barrier is gone too: a WG's poll
// for t+1 can't complete until its own slowest wave stored t+1, and that
// store is the wave's last h_lds access (WAR-safe).
// Poller side: 8B agent-atomic tagged-word polling (measured-best flavor),
// per-lane early exit once tags match. 8 replicas; WG polls replica wg&7
// (16 WGs/replica line vs 32 in R5). Depth-2 ring safe as before; tags
// 1..455 never collide with 0xAA poison.
// ---------------------------------------------------------------------------

#define HID   2048
#define T_ENC 365
#define F_DEC 90
#define NWG   128
#define NTH   512
#define SLOT  8192   // u64s per ring slot (8 replicas x 1024)

// ws layout (4-byte units)
#define WS_P    0        // p[6144]
#define WS_Q    6144     // q[6144]
#define WS_HBUF 12288    // u64 hbuf[2][8][1024]
#define WS_DX0  45056    // u64 dx0[8][1024]
#define WS_HST  61440    // __half hstore[90][2048]

typedef unsigned long long u64;

__device__ __forceinline__ float sigm(float x) {
    return 1.0f / (1.0f + __expf(-x));
}
__device__ __forceinline__ float tanh_f(float x) {
    return 1.0f - 2.0f / (1.0f + __expf(2.0f * x));
}
__device__ __forceinline__ unsigned packh(float lo, float hi) {
    __half2 h2 = __floats2half2_rn(lo, hi);
    return *(unsigned*)&h2;
}
__device__ __forceinline__ float2 unpkh(unsigned u) {
    return __half22float2(*(__half2*)&u);
}

__device__ __forceinline__ u64 tld(const u64* p) {
    return __hip_atomic_load((u64*)p, __ATOMIC_RELAXED, __HIP_MEMORY_SCOPE_AGENT);
}
__device__ __forceinline__ void tst(u64* p, u64 v) {
    __hip_atomic_store(p, v, __ATOMIC_RELAXED, __HIP_MEMORY_SCOPE_AGENT);
}
__device__ __forceinline__ u64 mk16(unsigned tag, float lo, float hi) {
    return ((u64)tag << 32) | (u64)packh(lo, hi);
}

// Poll 1024 paired u64s in our replica; per-lane early exit (tag match =>
// payload is final for this step); unpack payloads into lds[2048].
__device__ __forceinline__ void poll_to_lds(const u64* __restrict__ rep,
                                            unsigned tag, int tid,
                                            float* __restrict__ lds) {
    const u64* p0 = rep + tid;
    const u64* p1 = rep + 512 + tid;
    u64 x0 = 0, x1 = 0;
    bool ok0 = false, ok1 = false;
    while (true) {
        if (!ok0) {
            x0 = tld(p0);
            ok0 = ((unsigned)(x0 >> 32) == tag);
        }
        if (!ok1) {
            x1 = tld(p1);
            ok1 = ((unsigned)(x1 >> 32) == tag);
        }
        if (__ballot(ok0 & ok1) == ~0ull) break;
    }
    *(float2*)(lds + 2 * tid) = unpkh((unsigned)x0);
    *(float2*)(lds + 1024 + 2 * tid) = unpkh((unsigned)x1);
}

// p[r] = enc_Wih[r,:] @ Wb ; q[r] = enc_Wih[r,:] @ bb + enc_bih[r]
__global__ void prep_pq(const float* __restrict__ Wih, const float* __restrict__ Wb,
                        const float* __restrict__ bb, const float* __restrict__ bih,
                        float* __restrict__ p, float* __restrict__ q) {
    int wave = threadIdx.x >> 6, lane = threadIdx.x & 63;
    int row = blockIdx.x * 4 + wave;
    const float* wr = Wih + (size_t)row * HID;
    float ap = 0.f, aq = 0.f;
    for (int k = lane; k < HID; k += 64) {
        float w = wr[k];
        ap += w * Wb[k];
        aq += w * bb[k];
    }
#pragma unroll
    for (int m = 1; m < 64; m <<= 1) {
        ap += __shfl_xor(ap, m);
        aq += __shfl_xor(aq, m);
    }
    if (lane == 0) {
        p[row] = ap;
        q[row] = aq + bih[row];
    }
}

__global__ __launch_bounds__(NTH, 2) void persist(
    const float* __restrict__ hu, const float* __restrict__ encWhh,
    const float* __restrict__ encBhh, const float* __restrict__ decWih,
    const float* __restrict__ decWhh, const float* __restrict__ decBih,
    const float* __restrict__ decBhh, const float* __restrict__ p,
    const float* __restrict__ q, u64* hbuf, u64* dx0, __half* hstore) {
    const int wg = blockIdx.x, tid = threadIdx.x;
    const int wave = tid >> 6, lane = tid & 63;
    const int j0 = wg * 16;
    const int ja = j0 + 2 * wave, jb = ja + 1;
    const int widx = wg * 8 + wave;  // this wave's word index in each replica
    const int myrep = wg & 7;

    __shared__ float h_lds[HID], x_lds[HID];
    __shared__ float p_l[48], q_l[48], ebhh[48], dbih[48], dbhh[48];
    __shared__ float u_l[T_ENC];

    // --- LDS preloads (once) ---
    for (int idx = tid; idx < T_ENC; idx += NTH) u_l[idx] = hu[idx];
    if (tid < 48) {
        int g = tid >> 4, uu = tid & 15;
        int r = g * HID + j0 + uu;
        p_l[tid] = p[r];
        q_l[tid] = q[r];
        ebhh[tid] = encBhh[r];
        dbih[tid] = decBih[r];
        dbhh[tid] = decBhh[r];
    }

    // --- encoder Whh rows (pair) -> fp16 registers: 6 rows/wave ---
    // lane covers k in {4*lane + 256*i + e | i=0..7, e=0..3}
    unsigned We[6][8][2];
#pragma unroll
    for (int g = 0; g < 3; g++)
#pragma unroll
        for (int e = 0; e < 2; e++) {
            const float* base = encWhh + (size_t)(g * HID + ja + e) * HID;
#pragma unroll
            for (int i = 0; i < 8; i++) {
                float4 w = *reinterpret_cast<const float4*>(base + 4 * lane + 256 * i);
                We[g * 2 + e][i][0] = packh(w.x, w.y);
                We[g * 2 + e][i][1] = packh(w.z, w.w);
            }
        }
    __syncthreads();

    // =========================== encoder: 365 steps =========================
    for (int t = 0; t < T_ENC; t++) {
        if (t == 0) {
            for (int idx = tid; idx < HID; idx += NTH) h_lds[idx] = 0.f;
        } else {
            poll_to_lds(hbuf + (t & 1) * SLOT + myrep * 1024, (unsigned)t, tid,
                        h_lds);
        }
        __syncthreads();

        float4 hreg[8];
#pragma unroll
        for (int i = 0; i < 8; i++)
            hreg[i] = *reinterpret_cast<const float4*>(&h_lds[4 * lane + 256 * i]);

        float d[6];
#pragma unroll
        for (int g = 0; g < 6; g++) {
            float a0 = 0.f, a1 = 0.f, a2 = 0.f, a3 = 0.f;
#pragma unroll
            for (int i = 0; i < 8; i++) {
                float2 w01 = unpkh(We[g][i][0]);
                float2 w23 = unpkh(We[g][i][1]);
                float4 h4 = hreg[i];
                a0 += w01.x * h4.x;
                a1 += w01.y * h4.y;
                a2 += w23.x * h4.z;
                a3 += w23.y * h4.w;
            }
            d[g] = (a0 + a1) + (a2 + a3);
        }
#pragma unroll
        for (int m = 1; m < 64; m <<= 1) {
#pragma unroll
            for (int g = 0; g < 6; g++) d[g] += __shfl_xor(d[g], m);
        }

        if (lane < 8) {  // all 8 lanes compute identically; lane l -> replica l
            float u = u_l[t];
            int ua = 2 * wave, ub = ua + 1;
            float ra = sigm(u * p_l[ua] + q_l[ua] + d[0] + ebhh[ua]);
            float za = sigm(u * p_l[16 + ua] + q_l[16 + ua] + d[2] + ebhh[16 + ua]);
            float ca = tanh_f(u * p_l[32 + ua] + q_l[32 + ua] +
                              ra * (d[4] + ebhh[32 + ua]));
            float hpa = (1.f - za) * ca + za * h_lds[ja];
            float rb = sigm(u * p_l[ub] + q_l[ub] + d[1] + ebhh[ub]);
            float zb = sigm(u * p_l[16 + ub] + q_l[16 + ub] + d[3] + ebhh[16 + ub]);
            float cb = tanh_f(u * p_l[32 + ub] + q_l[32 + ub] +
                              rb * (d[5] + ebhh[32 + ub]));
            float hpb = (1.f - zb) * cb + zb * h_lds[jb];
            tst(hbuf + ((t + 1) & 1) * SLOT + lane * 1024 + widx,
                mk16((unsigned)(t + 1), sigm(hpa), sigm(hpb)));
            if (t == T_ENC - 1)
                tst(dx0 + lane * 1024 + widx, mk16((unsigned)T_ENC, hpa, hpb));
        }
        // no trailing barrier: next poll can't finish before our slowest wave
        // stored, and that store is its last h_lds access.
    }

    // --- decoder Wih+Whh rows (pair) -> fp16 registers: 12 rows/wave ---
    unsigned Wd[12][8][2];
#pragma unroll
    for (int g = 0; g < 6; g++)
#pragma unroll
        for (int e = 0; e < 2; e++) {
            const float* src = (g < 3)
                ? decWih + (size_t)(g * HID + ja + e) * HID
                : decWhh + (size_t)((g - 3) * HID + ja + e) * HID;
#pragma unroll
            for (int i = 0; i < 8; i++) {
                float4 w = *reinterpret_cast<const float4*>(src + 4 * lane + 256 * i);
                Wd[g * 2 + e][i][0] = packh(w.x, w.y);
                Wd[g * 2 + e][i][1] = packh(w.z, w.w);
            }
        }

    // =========================== decoder: 90 steps ==========================
    for (int s = 0; s < F_DEC; s++) {
        unsigned rt = (unsigned)(T_ENC + s);
        poll_to_lds(hbuf + (rt & 1) * SLOT + myrep * 1024, rt, tid, h_lds);
        if (s == 0) poll_to_lds(dx0 + myrep * 1024, (unsigned)T_ENC, tid, x_lds);
        __syncthreads();

        float4 vh[8];
#pragma unroll
        for (int i = 0; i < 8; i++)
            vh[i] = *reinterpret_cast<const float4*>(&h_lds[4 * lane + 256 * i]);

        float d[12];
#pragma unroll
        for (int g = 0; g < 12; g++) {
            float a0 = 0.f, a1 = 0.f, a2 = 0.f, a3 = 0.f;
#pragma unroll
            for (int i = 0; i < 8; i++) {
                float2 w01 = unpkh(Wd[g][i][0]);
                float2 w23 = unpkh(Wd[g][i][1]);
                float4 v4 = (g < 6 && s == 0)
                    ? *reinterpret_cast<const float4*>(&x_lds[4 * lane + 256 * i])
                    : vh[i];
                a0 += w01.x * v4.x;
                a1 += w01.y * v4.y;
                a2 += w23.x * v4.z;
                a3 += w23.y * v4.w;
            }
            d[g] = (a0 + a1) + (a2 + a3);
        }
#pragma unroll
        for (int m = 1; m < 64; m <<= 1) {
#pragma unroll
            for (int g = 0; g < 12; g++) d[g] += __shfl_xor(d[g], m);
        }

        if (lane < 8) {
            int ua = 2 * wave, ub = ua + 1;
            float ra = sigm(d[0] + dbih[ua] + d[6] + dbhh[ua]);
            float za = sigm(d[2] + dbih[16 + ua] + d[8] + dbhh[16 + ua]);
            float ca = tanh_f(d[4] + dbih[32 + ua] + ra * (d[10] + dbhh[32 + ua]));
            float hpa = (1.f - za) * ca + za * h_lds[ja];
            float rb = sigm(d[1] + dbih[ub] + d[7] + dbhh[ub]);
            float zb = sigm(d[3] + dbih[16 + ub] + d[9] + dbhh[16 + ub]);
            float cb = tanh_f(d[5] + dbih[32 + ub] + rb * (d[11] + dbhh[32 + ub]));
            float hpb = (1.f - zb) * cb + zb * h_lds[jb];
            tst(hbuf + ((rt + 1) & 1) * SLOT + lane * 1024 + widx,
                mk16(rt + 1, hpa, hpb));
            if (lane == 0)
                *(__half2*)(hstore + (size_t)s * HID + ja) =
                    __floats2half2_rn(hpa, hpb);
        }
    }
}

__global__ void sird_k(const float* __restrict__ sird, const float* __restrict__ Wa,
                       const float* __restrict__ ba, const int* __restrict__ ts_p,
                       const __half* __restrict__ hstore, float* __restrict__ out) {
    __shared__ float bpre[96];
    int wave = threadIdx.x >> 6, lane = threadIdx.x & 63;
    const float4* wa4 = (const float4*)Wa;
    for (int s = wave; s < F_DEC; s += 8) {
        const uint4* hr = (const uint4*)(hstore + (size_t)s * HID);
        float acc = 0.f;
#pragma unroll
        for (int m = 0; m < 4; m++) {
            uint4 hh = hr[lane + 64 * m];
            float4 w0 = wa4[2 * (lane + 64 * m)];
            float4 w1 = wa4[2 * (lane + 64 * m) + 1];
            float2 f;
            f = __half22float2(*(__half2*)&hh.x);
            acc += w0.x * f.x + w0.y * f.y;
            f = __half22float2(*(__half2*)&hh.y);
            acc += w0.z * f.x + w0.w * f.y;
            f = __half22float2(*(__half2*)&hh.z);
            acc += w1.x * f.x + w1.y * f.y;
            f = __half22float2(*(__half2*)&hh.w);
            acc += w1.z * f.x + w1.w * f.y;
        }
#pragma unroll
        for (int m = 1; m < 64; m <<= 1) acc += __shfl_xor(acc, m);
        if (lane == 0) bpre[s] = acc;
    }
    __syncthreads();
    if (threadIdx.x == 0) {
        float s = sird[0], i = sird[1], r = sird[2], d = sird[3], n = sird[4];
        float bl = 0.f;
        for (int t = 0; t < F_DEC; t++) {
            float b = 1.f / (1.f + expf(-(bpre[t] + ba[0])));
            bl = b;
            float si = s * i * b / n, ir = i * 0.05f, id = i * 0.01f;
            s -= si;
            i += si - ir - id;
            r += ir;
            d += id;
        }
        int ts = ts_p[0];
        float* foo = out + 5;
        for (int t = 0; t < ts - 1; t++) {
            float si = s * i * bl / n, ir = i * 0.05f, id = i * 0.01f;
            s -= si;
            i += si - ir - id;
            r += ir;
            d += id;
            foo[t * 5 + 0] = s;
            foo[t * 5 + 1] = i;
            foo[t * 5 + 2] = r;
            foo[t * 5 + 3] = d;
            foo[t * 5 + 4] = n;
        }
        out[0] = s;
        out[1] = i;
        out[2] = r;
        out[3] = d;
        out[4] = n;
    }
}

extern "C" void kernel_launch(void* const* d_in, const int* in_sizes, int n_in,
                              void* d_out, int out_size, void* d_ws, size_t ws_size,
                              hipStream_t stream) {
    const float* hu = (const float*)d_in[0];
    const float* sird = (const float*)d_in[1];
    const int* ts = (const int*)d_in[2];
    const float* Wb = (const float*)d_in[3];
    const float* bb = (const float*)d_in[4];
    const float* eWih = (const float*)d_in[5];
    const float* eWhh = (const float*)d_in[6];
    const float* eBih = (const float*)d_in[7];
    const float* eBhh = (const float*)d_in[8];
    const float* dWih = (const float*)d_in[9];
    const float* dWhh = (const float*)d_in[10];
    const float* dBih = (const float*)d_in[11];
    const float* dBhh = (const float*)d_in[12];
    const float* Wa = (const float*)d_in[13];
    const float* ba = (const float*)d_in[14];

    float* wsf = (float*)d_ws;
    float* p = wsf + WS_P;
    float* q = wsf + WS_Q;
    u64* hbuf = (u64*)(wsf + WS_HBUF);
    u64* dx0 = (u64*)(wsf + WS_DX0);
    __half* hstore = (__half*)(wsf + WS_HST);

    hipLaunchKernelGGL(prep_pq, dim3(6144 / 4), dim3(256), 0, stream, eWih, Wb, bb,
                       eBih, p, q);
    hipLaunchKernelGGL(persist, dim3(NWG), dim3(NTH), 0, stream, hu, eWhh, eBhh,
                       dWih, dWhh, dBih, dBhh, p, q, hbuf, dx0, hstore);
    hipLaunchKernelGGL(sird_k, dim3(1), dim3(NTH), 0, stream, sird, Wa, ba, ts,
                       hstore, (float*)d_out);
}